// Round 5
// baseline (399.947 us; speedup 1.0000x reference)
//
#include <hip/hip_runtime.h>

typedef __attribute__((ext_vector_type(8))) short s8v;
typedef __attribute__((ext_vector_type(4))) short s4v;
typedef __attribute__((ext_vector_type(4))) float f4v;

#define MFMA16(a, b, c) __builtin_amdgcn_mfma_f32_16x16x32_bf16((a), (b), (c), 0, 0, 0)
#define AS1 __attribute__((address_space(1)))
#define AS3 __attribute__((address_space(3)))

__device__ __forceinline__ short f2bf(float f) {  // RNE
  union { float f; unsigned u; } v; v.f = f;
  unsigned r = v.u + 0x7FFFu + ((v.u >> 16) & 1u);
  return (short)(r >> 16);
}
__device__ __forceinline__ float bf2f(short s) {
  union { unsigned u; float f; } v; v.u = ((unsigned)(unsigned short)s) << 16;
  return v.f;
}
__device__ __forceinline__ unsigned fbits(float f) {
  union { float f; unsigned u; } v; v.f = f; return v.u;
}
__device__ __forceinline__ unsigned pack2(float hi, float lo) {
  return __builtin_amdgcn_perm(fbits(hi), fbits(lo), 0x07060302u);
}
__device__ __forceinline__ void gld16(const void* g, void* l) {
  __builtin_amdgcn_global_load_lds((const AS1 unsigned*)g, (AS3 unsigned*)l, 16, 0, 0);
}

// ---------- weight transpose + cast (all 4 weights, z selects) ----------
__global__ __launch_bounds__(256) void wtrans4(const float* __restrict__ W0,
                                               const float* __restrict__ W1,
                                               const float* __restrict__ W2,
                                               const float* __restrict__ W3,
                                               short* __restrict__ Wt) {
  const float* W = blockIdx.z == 0 ? W0 : blockIdx.z == 1 ? W1 : blockIdx.z == 2 ? W2 : W3;
  Wt += (size_t)blockIdx.z * 1048576;
  __shared__ float tile[64][65];
  const int r0 = blockIdx.y * 64, c0 = blockIdx.x * 64;
  const int t = threadIdx.x;
  for (int i = 0; i < 4; ++i) {
    int lin = t + i * 256;
    int row = lin >> 4, c4 = (lin & 15) << 2;
    float4 v = *(const float4*)(W + (size_t)(r0 + row) * 1024 + c0 + c4);
    tile[row][c4 + 0] = v.x; tile[row][c4 + 1] = v.y;
    tile[row][c4 + 2] = v.z; tile[row][c4 + 3] = v.w;
  }
  __syncthreads();
  for (int i = 0; i < 4; ++i) {
    int lin = t + i * 256;
    int nl = lin >> 4, k4 = (lin & 15) << 2;
    s4v sv = { f2bf(tile[k4 + 0][nl]), f2bf(tile[k4 + 1][nl]),
               f2bf(tile[k4 + 2][nl]), f2bf(tile[k4 + 3][nl]) };
    *(s4v*)&Wt[(size_t)(c0 + nl) * 1024 + r0 + k4] = sv;
  }
}

// ---------- GEMM: C[8192][1024] = A @ W + bias ----------
// CAST=1: A is f32, cast to bf16 during LDS staging (no separate cast pass).
// EPI=0 (QKV): z<2 -> bf16 [b][H][tok][D] (Q:scaled, K), z==2 -> bf16 [b][H][D][tok] (V).
// EPI=1: bf16 flat [row][1024] (attn out-proj, consumed by ln).
// All stores 16B via 2-pass LDS transpose in a reused 18KB buffer.
template <int CAST, int EPI>
__global__ __launch_bounds__(256) void gemm_bt(
    const float* __restrict__ Af0, const float* __restrict__ Af1,
    const float* __restrict__ Af2, const short* __restrict__ Ab,
    const short* __restrict__ Bt,
    const float* __restrict__ b0, const float* __restrict__ b1,
    const float* __restrict__ b2, float s0,
    short* __restrict__ outb) {
  __shared__ __align__(16) short As[128 * 32];
  __shared__ __align__(16) short Bs[128 * 32];
  __shared__ __align__(16) char Ebuf[18432];
  short (*Ta)[136] = (short(*)[136])Ebuf;   // [tok 64][feat 128]
  short (*Tv)[72]  = (short(*)[72])Ebuf;    // [feat 128][tok 64]

  const int z = blockIdx.z;
  const float* Af = (CAST && z == 1) ? Af1 : (CAST && z == 2) ? Af2 : Af0;
  Bt += (size_t)z * 1048576;
  outb += (size_t)z * 8388608;
  const float* bias = z == 0 ? b0 : z == 1 ? b1 : b2;
  const float scale = z == 0 ? s0 : 1.f;

  const int tid = threadIdx.x;
  const int lane = tid & 63, w = tid >> 6;
  const int quad = lane >> 4, l16 = lane & 15;
  const int wm = (w >> 1) * 64, wn = (w & 1) * 64;
  const int mBase = blockIdx.x * 128, nBase = blockIdx.y * 128;
  f4v acc[4][4] = {};

  // B staging (always bf16, global_load_lds)
  const int id0 = tid, id1 = tid + 256;
  const short* Bg0 = Bt + (size_t)((id0 >> 2) + nBase) * 1024 + ((id0 & 3) << 3);
  const short* Bg1 = Bt + (size_t)((id1 >> 2) + nBase) * 1024 + ((id1 & 3) << 3);
  // A staging
  const float* Ap[4];
  const short* Ag0 = nullptr; const short* Ag1 = nullptr;
  short* Al[4];
  if constexpr (CAST) {
    for (int i = 0; i < 4; ++i) {
      int id = tid + i * 256;
      Ap[i] = Af + (size_t)(mBase + (id >> 3)) * 1024 + ((id & 7) << 2);
      Al[i] = &As[(id >> 3) * 32 + ((id & 7) << 2)];
    }
  } else {
    Ag0 = Ab + (size_t)((id0 >> 2) + mBase) * 1024 + ((id0 & 3) << 3);
    Ag1 = Ab + (size_t)((id1 >> 2) + mBase) * 1024 + ((id1 & 3) << 3);
  }

  for (int kt = 0; kt < 32; ++kt) {
    __syncthreads();
    gld16(Bg0 + kt * 32, &Bs[id0 * 8]);
    gld16(Bg1 + kt * 32, &Bs[id1 * 8]);
    if constexpr (CAST) {
      for (int i = 0; i < 4; ++i) {
        float4 v = *(const float4*)(Ap[i] + kt * 32);
        s4v sv = { f2bf(v.x), f2bf(v.y), f2bf(v.z), f2bf(v.w) };
        *(s4v*)Al[i] = sv;
      }
    } else {
      gld16(Ag0 + kt * 32, &As[id0 * 8]);
      gld16(Ag1 + kt * 32, &As[id1 * 8]);
    }
    __syncthreads();
    s8v a[4], b[4];
    for (int mt = 0; mt < 4; ++mt) a[mt] = *(const s8v*)&As[(wm + mt * 16 + l16) * 32 + quad * 8];
    for (int nt = 0; nt < 4; ++nt) b[nt] = *(const s8v*)&Bs[(wn + nt * 16 + l16) * 32 + quad * 8];
    for (int mt = 0; mt < 4; ++mt)
      for (int nt = 0; nt < 4; ++nt)
        acc[mt][nt] = MFMA16(a[mt], b[nt], acc[mt][nt]);
  }

  const int bI = mBase >> 11, tok0 = mBase & 2047;
  const bool vpath = (EPI == 0) && (z == 2);
  for (int p = 0; p < 2; ++p) {
    __syncthreads();
    if ((w >> 1) == p) {
      for (int nt = 0; nt < 4; ++nt) {
        int featl = wn + nt * 16 + l16;
        float bs = bias[nBase + featl];
        for (int mt = 0; mt < 4; ++mt)
          for (int r = 0; r < 4; ++r) {
            short val = f2bf((acc[mt][nt][r] + bs) * scale);
            if (vpath) Tv[featl][mt * 16 + quad * 4 + r] = val;
            else       Ta[mt * 16 + quad * 4 + r][featl] = val;
          }
      }
    }
    __syncthreads();
    if (vpath) {
      for (int it = 0; it < 4; ++it) {
        int id = tid + it * 256;
        int f = id >> 3, t8 = (id & 7) << 3;
        s8v v = *(const s8v*)&Tv[f][t8];
        int gf = nBase + f, h = gf >> 6, d = gf & 63;
        *(s8v*)&outb[(((size_t)bI * 16 + h) * 64 + d) * 2048 + tok0 + p * 64 + t8] = v;
      }
    } else {
      for (int it = 0; it < 4; ++it) {
        int id = tid + it * 256;
        int tok = id >> 4, f8 = (id & 15) << 3;
        s8v v = *(const s8v*)&Ta[tok][f8];
        if constexpr (EPI == 1) {
          *(s8v*)&outb[(size_t)(mBase + p * 64 + tok) * 1024 + nBase + f8] = v;
        } else {
          int gf = nBase + f8, h = gf >> 6, d = gf & 63;
          *(s8v*)&outb[(((size_t)bI * 16 + h) * 2048 + tok0 + p * 64 + tok) * 64 + d] = v;
        }
      }
    }
  }
}

// ---------- flash attention: S^T scheme, P stays in registers ----------
__global__ __launch_bounds__(256, 2) void attn_kernel(
    const short* __restrict__ Qp, const short* __restrict__ Kp,
    const short* __restrict__ Vpt, short* __restrict__ Ctx) {
  __shared__ __align__(16) short Ks[64][72];
  __shared__ __align__(16) short Vt[64][72];

  const int tid = threadIdx.x, w = tid >> 6, lane = tid & 63;
  const int quad = lane >> 4, l16 = lane & 15;
  const int qt = blockIdx.x, bh = blockIdx.y;
  const short* Qb = Qp + (size_t)bh * 2048 * 64;
  const short* Kb = Kp + (size_t)bh * 2048 * 64;
  const short* Vb = Vpt + (size_t)bh * 64 * 2048;
  const int qbase = qt * 256 + w * 64;

  s8v qf[4][2];
#pragma unroll
  for (int mt = 0; mt < 4; ++mt)
#pragma unroll
    for (int h = 0; h < 2; ++h)
      qf[mt][h] = *(const s8v*)(Qb + (size_t)(qbase + mt * 16 + l16) * 64 + h * 32 + quad * 8);

  const s8v vone = {16256, 16256, 16256, 16256, 16256, 16256, 16256, 16256};
  f4v Oa[4][4] = {};
  f4v La[4] = {};

  for (int kv = 0; kv < 32; ++kv) {
    const int kv0 = kv * 64;
    __syncthreads();
#pragma unroll
    for (int i = 0; i < 2; ++i) {
      int id = tid + i * 256;
      int g = id >> 3, c8 = (id & 7) << 3;
      int p = (g & 32) | (((g >> 2) & 1) << 4) | (((g >> 3) & 3) << 2) | (g & 3);
      *(s8v*)&Ks[p][c8] = *(const s8v*)(Kb + (size_t)(kv0 + g) * 64 + c8);
      *(s8v*)&Vt[g][c8] = *(const s8v*)(Vb + (size_t)g * 2048 + kv0 + c8);
    }
    __syncthreads();

    s8v kf[4][2], vf[4][2];
#pragma unroll
    for (int T = 0; T < 4; ++T) {
      kf[T][0] = *(const s8v*)&Ks[T * 16 + l16][quad * 8];
      kf[T][1] = *(const s8v*)&Ks[T * 16 + l16][32 + quad * 8];
      vf[T][0] = *(const s8v*)&Vt[T * 16 + l16][quad * 8];
      vf[T][1] = *(const s8v*)&Vt[T * 16 + l16][32 + quad * 8];
    }

#pragma unroll
    for (int mt = 0; mt < 4; ++mt) {
      f4v s[4] = {};
#pragma unroll
      for (int T = 0; T < 4; ++T) {
        s[T] = MFMA16(kf[T][0], qf[mt][0], s[T]);
        s[T] = MFMA16(kf[T][1], qf[mt][1], s[T]);
      }
#pragma unroll
      for (int T = 0; T < 4; ++T)
#pragma unroll
        for (int r = 0; r < 4; ++r)
          s[T][r] = __builtin_amdgcn_exp2f(s[T][r]);
      s8v pf[2];
#pragma unroll
      for (int cp = 0; cp < 2; ++cp) {
        union { s8v v; unsigned u[4]; } pk;
        pk.u[0] = pack2(s[2 * cp][1], s[2 * cp][0]);
        pk.u[1] = pack2(s[2 * cp][3], s[2 * cp][2]);
        pk.u[2] = pack2(s[2 * cp + 1][1], s[2 * cp + 1][0]);
        pk.u[3] = pack2(s[2 * cp + 1][3], s[2 * cp + 1][2]);
        pf[cp] = pk.v;
      }
      La[mt] = MFMA16(pf[0], vone, La[mt]);
      La[mt] = MFMA16(pf[1], vone, La[mt]);
#pragma unroll
      for (int nt = 0; nt < 4; ++nt) {
        Oa[mt][nt] = MFMA16(pf[0], vf[nt][0], Oa[mt][nt]);
        Oa[mt][nt] = MFMA16(pf[1], vf[nt][1], Oa[mt][nt]);
      }
    }
  }

  const int b = bh >> 4, h = bh & 15;
#pragma unroll
  for (int mt = 0; mt < 4; ++mt)
#pragma unroll
    for (int r = 0; r < 4; ++r) {
      float inv = 1.f / La[mt][r];
      int q = qbase + mt * 16 + quad * 4 + r;
#pragma unroll
      for (int nt = 0; nt < 4; ++nt) {
        int d = nt * 16 + l16;
        Ctx[((size_t)b * 2048 + q) * 1024 + h * 64 + d] = f2bf(Oa[mt][nt][r] * inv);
      }
    }
}

// ---------- residual + LayerNorm (attn input in bf16) ----------
__global__ __launch_bounds__(256) void ln_kernel(
    const float* __restrict__ resid, const short* __restrict__ attnb,
    const float* __restrict__ gamma, const float* __restrict__ beta,
    float* __restrict__ out) {
  const int row = blockIdx.x, t = threadIdx.x;
  const float4 rv = *(const float4*)(resid + (size_t)row * 1024 + t * 4);
  const s4v av = *(const s4v*)(attnb + (size_t)row * 1024 + t * 4);
  float x0 = rv.x + bf2f(av[0]), x1 = rv.y + bf2f(av[1]);
  float x2 = rv.z + bf2f(av[2]), x3 = rv.w + bf2f(av[3]);
  float s = x0 + x1 + x2 + x3;
  float ss = x0 * x0 + x1 * x1 + x2 * x2 + x3 * x3;
  for (int off = 32; off > 0; off >>= 1) {
    s += __shfl_down(s, off, 64);
    ss += __shfl_down(ss, off, 64);
  }
  __shared__ float red[8];
  const int wid = t >> 6, lane = t & 63;
  if (lane == 0) { red[wid] = s; red[4 + wid] = ss; }
  __syncthreads();
  float S = red[0] + red[1] + red[2] + red[3];
  float SS = red[4] + red[5] + red[6] + red[7];
  float mu = S * (1.f / 1024.f);
  float var = SS * (1.f / 1024.f) - mu * mu;
  float rstd = rsqrtf(var + 1e-5f);
  const float4 g = *(const float4*)(gamma + t * 4);
  const float4 bb = *(const float4*)(beta + t * 4);
  float4 o;
  o.x = (x0 - mu) * rstd * g.x + bb.x;
  o.y = (x1 - mu) * rstd * g.y + bb.y;
  o.z = (x2 - mu) * rstd * g.z + bb.z;
  o.w = (x3 - mu) * rstd * g.w + bb.w;
  *(float4*)(out + (size_t)row * 1024 + t * 4) = o;
}

extern "C" void kernel_launch(void* const* d_in, const int* in_sizes, int n_in,
                              void* d_out, int out_size, void* d_ws, size_t ws_size,
                              hipStream_t stream) {
  const float* Qin = (const float*)d_in[0];
  const float* Kin = (const float*)d_in[1];
  const float* Vin = (const float*)d_in[2];
  const float* Wq = (const float*)d_in[3];
  const float* bq = (const float*)d_in[4];
  const float* Wk = (const float*)d_in[5];
  const float* bk = (const float*)d_in[6];
  const float* Wv = (const float*)d_in[7];
  const float* bv = (const float*)d_in[8];
  const float* Wo = (const float*)d_in[9];
  const float* bo = (const float*)d_in[10];
  const float* gamma = (const float*)d_in[11];
  const float* beta = (const float*)d_in[12];
  float* out = (float*)d_out;

  char* ws = (char*)d_ws;
  const size_t MB = 1024 * 1024;
  short* Qp    = (short*)(ws);            // 16MB  (Qp,Kp,Vpt contiguous: z*8.4M)
  short* Ctx   = (short*)(ws + 48 * MB);  // 16MB
  short* AOutB = (short*)(ws + 64 * MB);  // 16MB bf16
  short* Wt    = (short*)(ws + 80 * MB);  // 4 x 2MB

  wtrans4<<<dim3(16, 16, 4), 256, 0, stream>>>(Wq, Wk, Wv, Wo, Wt);

  const float qscale = 0.125f * 1.44269504f;  // 1/sqrt(64) * log2(e)

  // Q,K,V projections fused (cast inline); z=0:Q (scaled), 1:K, 2:V (transposed out)
  gemm_bt<1, 0><<<dim3(64, 8, 3), 256, 0, stream>>>(
      Qin, Kin, Vin, nullptr, Wt, bq, bk, bv, qscale, Qp);

  attn_kernel<<<dim3(8, 64), 256, 0, stream>>>(Qp, Qp + 8388608, Qp + 16777216, Ctx);

  gemm_bt<0, 1><<<dim3(64, 8, 1), 256, 0, stream>>>(
      nullptr, nullptr, nullptr, Ctx, Wt + 3 * 1048576, bo, bo, bo, 1.f, AOutB);

  ln_kernel<<<8192, 256, 0, stream>>>(Qin, AOutB, gamma, beta, out);
}

// Round 8
// 348.832 us; speedup vs baseline: 1.1465x; 1.1465x over previous
//
#include <hip/hip_runtime.h>

typedef __attribute__((ext_vector_type(8))) short s8v;
typedef __attribute__((ext_vector_type(4))) short s4v;
typedef __attribute__((ext_vector_type(4))) float f4v;

#define MFMA16(a, b, c) __builtin_amdgcn_mfma_f32_16x16x32_bf16((a), (b), (c), 0, 0, 0)
#define AS1 __attribute__((address_space(1)))
#define AS3 __attribute__((address_space(3)))

__device__ __forceinline__ short f2bf(float f) {  // RNE
  union { float f; unsigned u; } v; v.f = f;
  unsigned r = v.u + 0x7FFFu + ((v.u >> 16) & 1u);
  return (short)(r >> 16);
}
__device__ __forceinline__ float bf2f(short s) {
  union { unsigned u; float f; } v; v.u = ((unsigned)(unsigned short)s) << 16;
  return v.f;
}
__device__ __forceinline__ unsigned fbits(float f) {
  union { float f; unsigned u; } v; v.f = f; return v.u;
}
__device__ __forceinline__ unsigned pack2(float hi, float lo) {
  return __builtin_amdgcn_perm(fbits(hi), fbits(lo), 0x07060302u);
}
__device__ __forceinline__ void gld16(const void* g, void* l) {
  __builtin_amdgcn_global_load_lds((const AS1 unsigned*)g, (AS3 unsigned*)l, 16, 0, 0);
}

// ---------- weight transpose + cast (all 4 weights, z selects) ----------
__global__ __launch_bounds__(256) void wtrans4(const float* __restrict__ W0,
                                               const float* __restrict__ W1,
                                               const float* __restrict__ W2,
                                               const float* __restrict__ W3,
                                               short* __restrict__ Wt) {
  const float* W = blockIdx.z == 0 ? W0 : blockIdx.z == 1 ? W1 : blockIdx.z == 2 ? W2 : W3;
  Wt += (size_t)blockIdx.z * 1048576;
  __shared__ float tile[64][65];
  const int r0 = blockIdx.y * 64, c0 = blockIdx.x * 64;
  const int t = threadIdx.x;
  for (int i = 0; i < 4; ++i) {
    int lin = t + i * 256;
    int row = lin >> 4, c4 = (lin & 15) << 2;
    float4 v = *(const float4*)(W + (size_t)(r0 + row) * 1024 + c0 + c4);
    tile[row][c4 + 0] = v.x; tile[row][c4 + 1] = v.y;
    tile[row][c4 + 2] = v.z; tile[row][c4 + 3] = v.w;
  }
  __syncthreads();
  for (int i = 0; i < 4; ++i) {
    int lin = t + i * 256;
    int nl = lin >> 4, k4 = (lin & 15) << 2;
    s4v sv = { f2bf(tile[k4 + 0][nl]), f2bf(tile[k4 + 1][nl]),
               f2bf(tile[k4 + 2][nl]), f2bf(tile[k4 + 3][nl]) };
    *(s4v*)&Wt[(size_t)(c0 + nl) * 1024 + r0 + k4] = sv;
  }
}

// ---------- GEMM with double-buffered, prefetch-before-compute K-loop ----------
// LDS pool (shorts): buf b at b*8192; A at +0, B at +4096. Epilogue transpose
// buffer [128][136] aliases the whole pool (dbuf dead by then); all stores 16B.
template <int CAST, int EPI>
__global__ __launch_bounds__(256) void gemm_bt(
    const float* __restrict__ Af0, const float* __restrict__ Af1,
    const float* __restrict__ Af2, const short* __restrict__ Ab,
    const short* __restrict__ Bt,
    const float* __restrict__ b0, const float* __restrict__ b1,
    const float* __restrict__ b2, float s0,
    short* __restrict__ outb) {
  __shared__ __align__(16) short smem[17408];   // 34816 B

  const int z = blockIdx.z;
  const float* Af = (CAST && z == 1) ? Af1 : (CAST && z == 2) ? Af2 : Af0;
  Bt += (size_t)z * 1048576;
  outb += (size_t)z * 8388608;
  const float* bias = z == 0 ? b0 : z == 1 ? b1 : b2;
  const float scale = z == 0 ? s0 : 1.f;

  const int tid = threadIdx.x;
  const int lane = tid & 63, w = tid >> 6;
  const int quad = lane >> 4, l16 = lane & 15;
  const int wm = (w >> 1) * 64, wn = (w & 1) * 64;
  const int mBase = blockIdx.x * 128, nBase = blockIdx.y * 128;
  f4v acc[4][4] = {};

  const int id0 = tid, id1 = tid + 256;
  const short* Bg0 = Bt + (size_t)((id0 >> 2) + nBase) * 1024 + ((id0 & 3) << 3);
  const short* Bg1 = Bt + (size_t)((id1 >> 2) + nBase) * 1024 + ((id1 & 3) << 3);
  const short* Ag0 = nullptr; const short* Ag1 = nullptr;
  const float* Ap[4];
  int Aslot[4];
  if constexpr (CAST) {
#pragma unroll
    for (int i = 0; i < 4; ++i) {
      int id = tid + i * 256;
      Ap[i] = Af + (size_t)(mBase + (id >> 3)) * 1024 + ((id & 7) << 2);
      Aslot[i] = (id >> 3) * 32 + ((id & 7) << 2);
    }
  } else {
    Ag0 = Ab + (size_t)((id0 >> 2) + mBase) * 1024 + ((id0 & 3) << 3);
    Ag1 = Ab + (size_t)((id1 >> 2) + mBase) * 1024 + ((id1 & 3) << 3);
  }

  float4 apre[4];
  // ---- prologue: stage tile 0 into buf 0; start A(1) register prefetch ----
  if constexpr (CAST) {
#pragma unroll
    for (int i = 0; i < 4; ++i) apre[i] = *(const float4*)(Ap[i]);
#pragma unroll
    for (int i = 0; i < 4; ++i) {
      s4v sv = { f2bf(apre[i].x), f2bf(apre[i].y), f2bf(apre[i].z), f2bf(apre[i].w) };
      *(s4v*)&smem[Aslot[i]] = sv;
    }
#pragma unroll
    for (int i = 0; i < 4; ++i) apre[i] = *(const float4*)(Ap[i] + 32);
  } else {
    gld16(Ag0, &smem[id0 * 8]);
    gld16(Ag1, &smem[id1 * 8]);
  }
  gld16(Bg0, &smem[4096 + id0 * 8]);
  gld16(Bg1, &smem[4096 + id1 * 8]);

  for (int kt = 0; kt < 32; ++kt) {
    const int bo_ = (kt & 1) * 8192, nbo = bo_ ^ 8192;
    __syncthreads();   // drains tile-kt loads; frees nbuf for staging
    if (kt < 31) {
      gld16(Bg0 + (kt + 1) * 32, &smem[nbo + 4096 + id0 * 8]);
      gld16(Bg1 + (kt + 1) * 32, &smem[nbo + 4096 + id1 * 8]);
      if constexpr (CAST) {
#pragma unroll
        for (int i = 0; i < 4; ++i) {
          s4v sv = { f2bf(apre[i].x), f2bf(apre[i].y), f2bf(apre[i].z), f2bf(apre[i].w) };
          *(s4v*)&smem[nbo + Aslot[i]] = sv;
        }
        if (kt < 30) {
#pragma unroll
          for (int i = 0; i < 4; ++i) apre[i] = *(const float4*)(Ap[i] + (kt + 2) * 32);
        }
      } else {
        gld16(Ag0 + (kt + 1) * 32, &smem[nbo + id0 * 8]);
        gld16(Ag1 + (kt + 1) * 32, &smem[nbo + id1 * 8]);
      }
    }
    s8v a[4], b[4];
#pragma unroll
    for (int mt = 0; mt < 4; ++mt) a[mt] = *(const s8v*)&smem[bo_ + (wm + mt * 16 + l16) * 32 + quad * 8];
#pragma unroll
    for (int nt = 0; nt < 4; ++nt) b[nt] = *(const s8v*)&smem[bo_ + 4096 + (wn + nt * 16 + l16) * 32 + quad * 8];
#pragma unroll
    for (int mt = 0; mt < 4; ++mt)
#pragma unroll
      for (int nt = 0; nt < 4; ++nt)
        acc[mt][nt] = MFMA16(a[mt], b[nt], acc[mt][nt]);
  }

  // ---- single-pass epilogue: transpose via smem pool (dbuf is dead) ----
  __syncthreads();
  const int bI = mBase >> 11, tok0 = mBase & 2047;
  const bool vpath = (EPI == 0) && (z == 2);
  short (*Ta)[136] = (short(*)[136])smem;   // [tok 128][feat 128]
  short (*Tv)[136] = (short(*)[136])smem;   // [feat 128][tok 128]
  if (vpath) {
#pragma unroll
    for (int nt = 0; nt < 4; ++nt) {
      int featl = wn + nt * 16 + l16;
      float bs = bias[nBase + featl];
#pragma unroll
      for (int mt = 0; mt < 4; ++mt) {
        union { s4v v; unsigned u[2]; } pk;
        pk.u[0] = pack2(acc[mt][nt][1] + bs, acc[mt][nt][0] + bs);
        pk.u[1] = pack2(acc[mt][nt][3] + bs, acc[mt][nt][2] + bs);
        *(s4v*)&Tv[featl][wm + mt * 16 + quad * 4] = pk.v;
      }
    }
  } else {
#pragma unroll
    for (int nt = 0; nt < 4; ++nt) {
      int featl = wn + nt * 16 + l16;
      float bs = bias[nBase + featl];
#pragma unroll
      for (int mt = 0; mt < 4; ++mt)
#pragma unroll
        for (int r = 0; r < 4; ++r)
          Ta[wm + mt * 16 + quad * 4 + r][featl] = f2bf((acc[mt][nt][r] + bs) * scale);
    }
  }
  __syncthreads();
  if (vpath) {
    // 128 feats x 128 tokens = 2048 s8v chunks -> 8 iterations
#pragma unroll
    for (int it = 0; it < 8; ++it) {
      int id = tid + it * 256;
      int f = id >> 4, t8 = (id & 15) << 3;
      s8v v = *(const s8v*)&Tv[f][t8];
      int gf = nBase + f, h = gf >> 6, d = gf & 63;
      *(s8v*)&outb[(((size_t)bI * 16 + h) * 64 + d) * 2048 + tok0 + t8] = v;
    }
  } else {
#pragma unroll
    for (int it = 0; it < 8; ++it) {
      int id = tid + it * 256;
      int tok = id >> 4, f8 = (id & 15) << 3;
      s8v v = *(const s8v*)&Ta[tok][f8];
      if constexpr (EPI == 1) {
        *(s8v*)&outb[(size_t)(mBase + tok) * 1024 + nBase + f8] = v;
      } else {
        int gf = nBase + f8, h = gf >> 6, d = gf & 63;
        *(s8v*)&outb[(((size_t)bI * 16 + h) * 2048 + tok0 + tok) * 64 + d] = v;
      }
    }
  }
}

// ---------- flash attention: S^T scheme, P stays in registers ----------
__global__ __launch_bounds__(256, 2) void attn_kernel(
    const short* __restrict__ Qp, const short* __restrict__ Kp,
    const short* __restrict__ Vpt, short* __restrict__ Ctx) {
  __shared__ __align__(16) short Ks[64][72];
  __shared__ __align__(16) short Vt[64][72];

  const int tid = threadIdx.x, w = tid >> 6, lane = tid & 63;
  const int quad = lane >> 4, l16 = lane & 15;
  const int qt = blockIdx.x, bh = blockIdx.y;
  const short* Qb = Qp + (size_t)bh * 2048 * 64;
  const short* Kb = Kp + (size_t)bh * 2048 * 64;
  const short* Vb = Vpt + (size_t)bh * 64 * 2048;
  const int qbase = qt * 256 + w * 64;

  s8v qf[4][2];
#pragma unroll
  for (int mt = 0; mt < 4; ++mt)
#pragma unroll
    for (int h = 0; h < 2; ++h)
      qf[mt][h] = *(const s8v*)(Qb + (size_t)(qbase + mt * 16 + l16) * 64 + h * 32 + quad * 8);

  const s8v vone = {16256, 16256, 16256, 16256, 16256, 16256, 16256, 16256};
  f4v Oa[4][4] = {};
  f4v La[4] = {};

  for (int kv = 0; kv < 32; ++kv) {
    const int kv0 = kv * 64;
    __syncthreads();
#pragma unroll
    for (int i = 0; i < 2; ++i) {
      int id = tid + i * 256;
      int g = id >> 3, c8 = (id & 7) << 3;
      int p = (g & 32) | (((g >> 2) & 1) << 4) | (((g >> 3) & 3) << 2) | (g & 3);
      *(s8v*)&Ks[p][c8] = *(const s8v*)(Kb + (size_t)(kv0 + g) * 64 + c8);
      *(s8v*)&Vt[g][c8] = *(const s8v*)(Vb + (size_t)g * 2048 + kv0 + c8);
    }
    __syncthreads();

    s8v kf[4][2], vf[4][2];
#pragma unroll
    for (int T = 0; T < 4; ++T) {
      kf[T][0] = *(const s8v*)&Ks[T * 16 + l16][quad * 8];
      kf[T][1] = *(const s8v*)&Ks[T * 16 + l16][32 + quad * 8];
      vf[T][0] = *(const s8v*)&Vt[T * 16 + l16][quad * 8];
      vf[T][1] = *(const s8v*)&Vt[T * 16 + l16][32 + quad * 8];
    }

#pragma unroll
    for (int mt = 0; mt < 4; ++mt) {
      f4v s[4] = {};
#pragma unroll
      for (int T = 0; T < 4; ++T) {
        s[T] = MFMA16(kf[T][0], qf[mt][0], s[T]);
        s[T] = MFMA16(kf[T][1], qf[mt][1], s[T]);
      }
#pragma unroll
      for (int T = 0; T < 4; ++T)
#pragma unroll
        for (int r = 0; r < 4; ++r)
          s[T][r] = __builtin_amdgcn_exp2f(s[T][r]);
      s8v pf[2];
#pragma unroll
      for (int cp = 0; cp < 2; ++cp) {
        union { s8v v; unsigned u[4]; } pk;
        pk.u[0] = pack2(s[2 * cp][1], s[2 * cp][0]);
        pk.u[1] = pack2(s[2 * cp][3], s[2 * cp][2]);
        pk.u[2] = pack2(s[2 * cp + 1][1], s[2 * cp + 1][0]);
        pk.u[3] = pack2(s[2 * cp + 1][3], s[2 * cp + 1][2]);
        pf[cp] = pk.v;
      }
      La[mt] = MFMA16(pf[0], vone, La[mt]);
      La[mt] = MFMA16(pf[1], vone, La[mt]);
#pragma unroll
      for (int nt = 0; nt < 4; ++nt) {
        Oa[mt][nt] = MFMA16(pf[0], vf[nt][0], Oa[mt][nt]);
        Oa[mt][nt] = MFMA16(pf[1], vf[nt][1], Oa[mt][nt]);
      }
    }
  }

  const int b = bh >> 4, h = bh & 15;
#pragma unroll
  for (int mt = 0; mt < 4; ++mt)
#pragma unroll
    for (int r = 0; r < 4; ++r) {
      float inv = 1.f / La[mt][r];
      int q = qbase + mt * 16 + quad * 4 + r;
#pragma unroll
      for (int nt = 0; nt < 4; ++nt) {
        int d = nt * 16 + l16;
        Ctx[((size_t)b * 2048 + q) * 1024 + h * 64 + d] = f2bf(Oa[mt][nt][r] * inv);
      }
    }
}

// ---------- residual + LayerNorm (attn input in bf16) ----------
__global__ __launch_bounds__(256) void ln_kernel(
    const float* __restrict__ resid, const short* __restrict__ attnb,
    const float* __restrict__ gamma, const float* __restrict__ beta,
    float* __restrict__ out) {
  const int row = blockIdx.x, t = threadIdx.x;
  const float4 rv = *(const float4*)(resid + (size_t)row * 1024 + t * 4);
  const s4v av = *(const s4v*)(attnb + (size_t)row * 1024 + t * 4);
  float x0 = rv.x + bf2f(av[0]), x1 = rv.y + bf2f(av[1]);
  float x2 = rv.z + bf2f(av[2]), x3 = rv.w + bf2f(av[3]);
  float s = x0 + x1 + x2 + x3;
  float ss = x0 * x0 + x1 * x1 + x2 * x2 + x3 * x3;
  for (int off = 32; off > 0; off >>= 1) {
    s += __shfl_down(s, off, 64);
    ss += __shfl_down(ss, off, 64);
  }
  __shared__ float red[8];
  const int wid = t >> 6, lane = t & 63;
  if (lane == 0) { red[wid] = s; red[4 + wid] = ss; }
  __syncthreads();
  float S = red[0] + red[1] + red[2] + red[3];
  float SS = red[4] + red[5] + red[6] + red[7];
  float mu = S * (1.f / 1024.f);
  float var = SS * (1.f / 1024.f) - mu * mu;
  float rstd = rsqrtf(var + 1e-5f);
  const float4 g = *(const float4*)(gamma + t * 4);
  const float4 bb = *(const float4*)(beta + t * 4);
  float4 o;
  o.x = (x0 - mu) * rstd * g.x + bb.x;
  o.y = (x1 - mu) * rstd * g.y + bb.y;
  o.z = (x2 - mu) * rstd * g.z + bb.z;
  o.w = (x3 - mu) * rstd * g.w + bb.w;
  *(float4*)(out + (size_t)row * 1024 + t * 4) = o;
}

extern "C" void kernel_launch(void* const* d_in, const int* in_sizes, int n_in,
                              void* d_out, int out_size, void* d_ws, size_t ws_size,
                              hipStream_t stream) {
  const float* Qin = (const float*)d_in[0];
  const float* Kin = (const float*)d_in[1];
  const float* Vin = (const float*)d_in[2];
  const float* Wq = (const float*)d_in[3];
  const float* bq = (const float*)d_in[4];
  const float* Wk = (const float*)d_in[5];
  const float* bk = (const float*)d_in[6];
  const float* Wv = (const float*)d_in[7];
  const float* bv = (const float*)d_in[8];
  const float* Wo = (const float*)d_in[9];
  const float* bo = (const float*)d_in[10];
  const float* gamma = (const float*)d_in[11];
  const float* beta = (const float*)d_in[12];
  float* out = (float*)d_out;

  char* ws = (char*)d_ws;
  const size_t MB = 1024 * 1024;
  short* Qp    = (short*)(ws);            // Qp,Kp,Vpt contiguous at z*8388608
  short* Ctx   = (short*)(ws + 48 * MB);
  short* AOutB = (short*)(ws + 64 * MB);
  short* Wt    = (short*)(ws + 80 * MB);  // 4 x 2MB

  wtrans4<<<dim3(16, 16, 4), 256, 0, stream>>>(Wq, Wk, Wv, Wo, Wt);

  const float qscale = 0.125f * 1.44269504f;  // 1/sqrt(64) * log2(e)

  gemm_bt<1, 0><<<dim3(64, 8, 3), 256, 0, stream>>>(
      Qin, Kin, Vin, nullptr, Wt, bq, bk, bv, qscale, Qp);

  attn_kernel<<<dim3(8, 64), 256, 0, stream>>>(Qp, Qp + 8388608, Qp + 16777216, Ctx);

  gemm_bt<0, 1><<<dim3(64, 8, 1), 256, 0, stream>>>(
      nullptr, nullptr, nullptr, Ctx, Wt + 3 * 1048576, bo, bo, bo, 1.f, AOutB);

  ln_kernel<<<8192, 256, 0, stream>>>(Qin, AOutB, gamma, beta, out);
}

// Round 9
// 348.574 us; speedup vs baseline: 1.1474x; 1.0007x over previous
//
#include <hip/hip_runtime.h>

typedef __attribute__((ext_vector_type(8))) short s8v;
typedef __attribute__((ext_vector_type(4))) short s4v;
typedef __attribute__((ext_vector_type(4))) float f4v;

#define MFMA16(a, b, c) __builtin_amdgcn_mfma_f32_16x16x32_bf16((a), (b), (c), 0, 0, 0)
#define AS1 __attribute__((address_space(1)))
#define AS3 __attribute__((address_space(3)))

__device__ __forceinline__ short f2bf(float f) {  // RNE
  union { float f; unsigned u; } v; v.f = f;
  unsigned r = v.u + 0x7FFFu + ((v.u >> 16) & 1u);
  return (short)(r >> 16);
}
__device__ __forceinline__ float bf2f(short s) {
  union { unsigned u; float f; } v; v.u = ((unsigned)(unsigned short)s) << 16;
  return v.f;
}
__device__ __forceinline__ unsigned fbits(float f) {
  union { float f; unsigned u; } v; v.f = f; return v.u;
}
// pack two f32 -> dword of two bf16 (truncate)
__device__ __forceinline__ unsigned pack2(float hi, float lo) {
  return __builtin_amdgcn_perm(fbits(hi), fbits(lo), 0x07060302u);
}
// pack two f32 -> dword of two bf16 (round-half-up): 3 VALU ops total
__device__ __forceinline__ unsigned pack2rn(float hi, float lo) {
  return __builtin_amdgcn_perm(fbits(hi) + 0x8000u, fbits(lo) + 0x8000u, 0x07060302u);
}
__device__ __forceinline__ void gld16(const void* g, void* l) {
  __builtin_amdgcn_global_load_lds((const AS1 unsigned*)g, (AS3 unsigned*)l, 16, 0, 0);
}

// ---------- weight transpose + cast (all 4 weights, z selects) ----------
__global__ __launch_bounds__(256) void wtrans4(const float* __restrict__ W0,
                                               const float* __restrict__ W1,
                                               const float* __restrict__ W2,
                                               const float* __restrict__ W3,
                                               short* __restrict__ Wt) {
  const float* W = blockIdx.z == 0 ? W0 : blockIdx.z == 1 ? W1 : blockIdx.z == 2 ? W2 : W3;
  Wt += (size_t)blockIdx.z * 1048576;
  __shared__ float tile[64][65];
  const int r0 = blockIdx.y * 64, c0 = blockIdx.x * 64;
  const int t = threadIdx.x;
  for (int i = 0; i < 4; ++i) {
    int lin = t + i * 256;
    int row = lin >> 4, c4 = (lin & 15) << 2;
    float4 v = *(const float4*)(W + (size_t)(r0 + row) * 1024 + c0 + c4);
    tile[row][c4 + 0] = v.x; tile[row][c4 + 1] = v.y;
    tile[row][c4 + 2] = v.z; tile[row][c4 + 3] = v.w;
  }
  __syncthreads();
  for (int i = 0; i < 4; ++i) {
    int lin = t + i * 256;
    int nl = lin >> 4, k4 = (lin & 15) << 2;
    s4v sv = { f2bf(tile[k4 + 0][nl]), f2bf(tile[k4 + 1][nl]),
               f2bf(tile[k4 + 2][nl]), f2bf(tile[k4 + 3][nl]) };
    *(s4v*)&Wt[(size_t)(c0 + nl) * 1024 + r0 + k4] = sv;
  }
}

// ---------- GEMM with double-buffered, prefetch-before-compute K-loop ----------
// LDS pool (shorts): buf b at b*8192; A at +0, B at +4096. Epilogue transpose
// buffer [128][136] aliases the whole pool (dbuf dead by then); all stores 16B.
template <int CAST, int EPI>
__global__ __launch_bounds__(256) void gemm_bt(
    const float* __restrict__ Af0, const float* __restrict__ Af1,
    const float* __restrict__ Af2, const short* __restrict__ Ab,
    const short* __restrict__ Bt,
    const float* __restrict__ b0, const float* __restrict__ b1,
    const float* __restrict__ b2, float s0,
    short* __restrict__ outb) {
  __shared__ __align__(16) short smem[17408];   // 34816 B

  const int z = blockIdx.z;
  const float* Af = (CAST && z == 1) ? Af1 : (CAST && z == 2) ? Af2 : Af0;
  Bt += (size_t)z * 1048576;
  outb += (size_t)z * 8388608;
  const float* bias = z == 0 ? b0 : z == 1 ? b1 : b2;
  const float scale = z == 0 ? s0 : 1.f;

  const int tid = threadIdx.x;
  const int lane = tid & 63, w = tid >> 6;
  const int quad = lane >> 4, l16 = lane & 15;
  const int wm = (w >> 1) * 64, wn = (w & 1) * 64;
  const int mBase = blockIdx.x * 128, nBase = blockIdx.y * 128;
  f4v acc[4][4] = {};

  const int id0 = tid, id1 = tid + 256;
  const short* Bg0 = Bt + (size_t)((id0 >> 2) + nBase) * 1024 + ((id0 & 3) << 3);
  const short* Bg1 = Bt + (size_t)((id1 >> 2) + nBase) * 1024 + ((id1 & 3) << 3);
  const short* Ag0 = nullptr; const short* Ag1 = nullptr;
  const float* Ap[4];
  int Aslot[4];
  if constexpr (CAST) {
#pragma unroll
    for (int i = 0; i < 4; ++i) {
      int id = tid + i * 256;
      Ap[i] = Af + (size_t)(mBase + (id >> 3)) * 1024 + ((id & 7) << 2);
      Aslot[i] = (id >> 3) * 32 + ((id & 7) << 2);
    }
  } else {
    Ag0 = Ab + (size_t)((id0 >> 2) + mBase) * 1024 + ((id0 & 3) << 3);
    Ag1 = Ab + (size_t)((id1 >> 2) + mBase) * 1024 + ((id1 & 3) << 3);
  }

  float4 apre[4];
  // ---- prologue: stage tile 0 into buf 0; start A(1) register prefetch ----
  if constexpr (CAST) {
#pragma unroll
    for (int i = 0; i < 4; ++i) apre[i] = *(const float4*)(Ap[i]);
#pragma unroll
    for (int i = 0; i < 4; ++i) {
      union { s4v v; unsigned u[2]; } pk;
      pk.u[0] = pack2rn(apre[i].y, apre[i].x);
      pk.u[1] = pack2rn(apre[i].w, apre[i].z);
      *(s4v*)&smem[Aslot[i]] = pk.v;
    }
#pragma unroll
    for (int i = 0; i < 4; ++i) apre[i] = *(const float4*)(Ap[i] + 32);
  } else {
    gld16(Ag0, &smem[id0 * 8]);
    gld16(Ag1, &smem[id1 * 8]);
  }
  gld16(Bg0, &smem[4096 + id0 * 8]);
  gld16(Bg1, &smem[4096 + id1 * 8]);

  for (int kt = 0; kt < 32; ++kt) {
    const int bo_ = (kt & 1) * 8192, nbo = bo_ ^ 8192;
    __syncthreads();   // drains tile-kt loads; frees nbuf for staging
    if (kt < 31) {
      gld16(Bg0 + (kt + 1) * 32, &smem[nbo + 4096 + id0 * 8]);
      gld16(Bg1 + (kt + 1) * 32, &smem[nbo + 4096 + id1 * 8]);
      if constexpr (CAST) {
#pragma unroll
        for (int i = 0; i < 4; ++i) {
          union { s4v v; unsigned u[2]; } pk;
          pk.u[0] = pack2rn(apre[i].y, apre[i].x);
          pk.u[1] = pack2rn(apre[i].w, apre[i].z);
          *(s4v*)&smem[nbo + Aslot[i]] = pk.v;
        }
        if (kt < 30) {
#pragma unroll
          for (int i = 0; i < 4; ++i) apre[i] = *(const float4*)(Ap[i] + (kt + 2) * 32);
        }
      } else {
        gld16(Ag0 + (kt + 1) * 32, &smem[nbo + id0 * 8]);
        gld16(Ag1 + (kt + 1) * 32, &smem[nbo + id1 * 8]);
      }
    }
    s8v a[4], b[4];
#pragma unroll
    for (int mt = 0; mt < 4; ++mt) a[mt] = *(const s8v*)&smem[bo_ + (wm + mt * 16 + l16) * 32 + quad * 8];
#pragma unroll
    for (int nt = 0; nt < 4; ++nt) b[nt] = *(const s8v*)&smem[bo_ + 4096 + (wn + nt * 16 + l16) * 32 + quad * 8];
#pragma unroll
    for (int mt = 0; mt < 4; ++mt)
#pragma unroll
      for (int nt = 0; nt < 4; ++nt)
        acc[mt][nt] = MFMA16(a[mt], b[nt], acc[mt][nt]);
  }

  // ---- single-pass epilogue: transpose via smem pool (dbuf is dead) ----
  __syncthreads();
  const int bI = mBase >> 11, tok0 = mBase & 2047;
  const bool vpath = (EPI == 0) && (z == 2);
  short (*Ta)[136] = (short(*)[136])smem;   // [tok 128][feat 128]
  short (*Tv)[136] = (short(*)[136])smem;   // [feat 128][tok 128]
  if (vpath) {
#pragma unroll
    for (int nt = 0; nt < 4; ++nt) {
      int featl = wn + nt * 16 + l16;
      float bs = bias[nBase + featl];
#pragma unroll
      for (int mt = 0; mt < 4; ++mt) {
        union { s4v v; unsigned u[2]; } pk;
        pk.u[0] = pack2(acc[mt][nt][1] + bs, acc[mt][nt][0] + bs);
        pk.u[1] = pack2(acc[mt][nt][3] + bs, acc[mt][nt][2] + bs);
        *(s4v*)&Tv[featl][wm + mt * 16 + quad * 4] = pk.v;
      }
    }
  } else {
#pragma unroll
    for (int nt = 0; nt < 4; ++nt) {
      int featl = wn + nt * 16 + l16;
      float bs = bias[nBase + featl];
#pragma unroll
      for (int mt = 0; mt < 4; ++mt)
#pragma unroll
        for (int r = 0; r < 4; ++r)
          Ta[wm + mt * 16 + quad * 4 + r][featl] = f2bf((acc[mt][nt][r] + bs) * scale);
    }
  }
  __syncthreads();
  if (vpath) {
#pragma unroll
    for (int it = 0; it < 8; ++it) {
      int id = tid + it * 256;
      int f = id >> 4, t8 = (id & 15) << 3;
      s8v v = *(const s8v*)&Tv[f][t8];
      int gf = nBase + f, h = gf >> 6, d = gf & 63;
      *(s8v*)&outb[(((size_t)bI * 16 + h) * 64 + d) * 2048 + tok0 + t8] = v;
    }
  } else {
#pragma unroll
    for (int it = 0; it < 8; ++it) {
      int id = tid + it * 256;
      int tok = id >> 4, f8 = (id & 15) << 3;
      s8v v = *(const s8v*)&Ta[tok][f8];
      if constexpr (EPI == 1) {
        *(s8v*)&outb[(size_t)(mBase + tok) * 1024 + nBase + f8] = v;
      } else {
        int gf = nBase + f8, h = gf >> 6, d = gf & 63;
        *(s8v*)&outb[(((size_t)bI * 16 + h) * 2048 + tok0 + tok) * 64 + d] = v;
      }
    }
  }
}

// ---------- flash attention: S^T scheme, P in registers, dbuf K/V staging ----------
__global__ __launch_bounds__(256, 2) void attn_kernel(
    const short* __restrict__ Qp, const short* __restrict__ Kp,
    const short* __restrict__ Vpt, short* __restrict__ Ctx) {
  __shared__ __align__(16) short Ks[2][64][72];
  __shared__ __align__(16) short Vt[2][64][72];

  const int tid = threadIdx.x, w = tid >> 6, lane = tid & 63;
  const int quad = lane >> 4, l16 = lane & 15;
  const int qt = blockIdx.x, bh = blockIdx.y;
  const short* Qb = Qp + (size_t)bh * 2048 * 64;
  const short* Kb = Kp + (size_t)bh * 2048 * 64;
  const short* Vb = Vpt + (size_t)bh * 64 * 2048;
  const int qbase = qt * 256 + w * 64;

  // staging indices (2 chunks per thread)
  int sg[2], sc8[2], sp[2];
  const short* Ksrc[2];
  const short* Vsrc[2];
#pragma unroll
  for (int i = 0; i < 2; ++i) {
    int id = tid + i * 256;
    int g = id >> 3, c8 = (id & 7) << 3;
    int p = (g & 32) | (((g >> 2) & 1) << 4) | (((g >> 3) & 3) << 2) | (g & 3);
    sg[i] = g; sc8[i] = c8; sp[i] = p;
    Ksrc[i] = Kb + (size_t)g * 64 + c8;     // +kv*4096 per tile
    Vsrc[i] = Vb + (size_t)g * 2048 + c8;   // +kv*64 per tile
  }

  s8v qf[4][2];
#pragma unroll
  for (int mt = 0; mt < 4; ++mt)
#pragma unroll
    for (int h = 0; h < 2; ++h)
      qf[mt][h] = *(const s8v*)(Qb + (size_t)(qbase + mt * 16 + l16) * 64 + h * 32 + quad * 8);

  // prologue: stage kv=0 into buf 0
  {
    s8v kr[2], vr[2];
#pragma unroll
    for (int i = 0; i < 2; ++i) { kr[i] = *(const s8v*)Ksrc[i]; vr[i] = *(const s8v*)Vsrc[i]; }
#pragma unroll
    for (int i = 0; i < 2; ++i) {
      *(s8v*)&Ks[0][sp[i]][sc8[i]] = kr[i];
      *(s8v*)&Vt[0][sg[i]][sc8[i]] = vr[i];
    }
  }

  const s8v vone = {16256, 16256, 16256, 16256, 16256, 16256, 16256, 16256};
  f4v Oa[4][4] = {};
  f4v La[4] = {};

  for (int kv = 0; kv < 32; ++kv) {
    const int buf = kv & 1;
    s8v kn[2], vn[2];
    if (kv < 31) {
#pragma unroll
      for (int i = 0; i < 2; ++i) {
        kn[i] = *(const s8v*)(Ksrc[i] + (size_t)(kv + 1) * 4096);
        vn[i] = *(const s8v*)(Vsrc[i] + (size_t)(kv + 1) * 64);
      }
    }
    __syncthreads();   // buf's staging writes (prev iter) visible

    s8v kf[4][2], vf[4][2];
#pragma unroll
    for (int T = 0; T < 4; ++T) {
      kf[T][0] = *(const s8v*)&Ks[buf][T * 16 + l16][quad * 8];
      kf[T][1] = *(const s8v*)&Ks[buf][T * 16 + l16][32 + quad * 8];
      vf[T][0] = *(const s8v*)&Vt[buf][T * 16 + l16][quad * 8];
      vf[T][1] = *(const s8v*)&Vt[buf][T * 16 + l16][32 + quad * 8];
    }

#pragma unroll
    for (int mt = 0; mt < 4; ++mt) {
      f4v s[4] = {};
#pragma unroll
      for (int T = 0; T < 4; ++T) {
        s[T] = MFMA16(kf[T][0], qf[mt][0], s[T]);
        s[T] = MFMA16(kf[T][1], qf[mt][1], s[T]);
      }
#pragma unroll
      for (int T = 0; T < 4; ++T)
#pragma unroll
        for (int r = 0; r < 4; ++r)
          s[T][r] = __builtin_amdgcn_exp2f(s[T][r]);
      s8v pf[2];
#pragma unroll
      for (int cp = 0; cp < 2; ++cp) {
        union { s8v v; unsigned u[4]; } pk;
        pk.u[0] = pack2(s[2 * cp][1], s[2 * cp][0]);
        pk.u[1] = pack2(s[2 * cp][3], s[2 * cp][2]);
        pk.u[2] = pack2(s[2 * cp + 1][1], s[2 * cp + 1][0]);
        pk.u[3] = pack2(s[2 * cp + 1][3], s[2 * cp + 1][2]);
        pf[cp] = pk.v;
      }
      La[mt] = MFMA16(pf[0], vone, La[mt]);
      La[mt] = MFMA16(pf[1], vone, La[mt]);
#pragma unroll
      for (int nt = 0; nt < 4; ++nt) {
        Oa[mt][nt] = MFMA16(pf[0], vf[nt][0], Oa[mt][nt]);
        Oa[mt][nt] = MFMA16(pf[1], vf[nt][1], Oa[mt][nt]);
      }
    }

    if (kv < 31) {
#pragma unroll
      for (int i = 0; i < 2; ++i) {
        *(s8v*)&Ks[buf ^ 1][sp[i]][sc8[i]] = kn[i];
        *(s8v*)&Vt[buf ^ 1][sg[i]][sc8[i]] = vn[i];
      }
    }
  }

  const int b = bh >> 4, h = bh & 15;
#pragma unroll
  for (int mt = 0; mt < 4; ++mt)
#pragma unroll
    for (int r = 0; r < 4; ++r) {
      float inv = 1.f / La[mt][r];
      int q = qbase + mt * 16 + quad * 4 + r;
#pragma unroll
      for (int nt = 0; nt < 4; ++nt) {
        int d = nt * 16 + l16;
        Ctx[((size_t)b * 2048 + q) * 1024 + h * 64 + d] = f2bf(Oa[mt][nt][r] * inv);
      }
    }
}

// ---------- residual + LayerNorm (attn input in bf16) ----------
__global__ __launch_bounds__(256) void ln_kernel(
    const float* __restrict__ resid, const short* __restrict__ attnb,
    const float* __restrict__ gamma, const float* __restrict__ beta,
    float* __restrict__ out) {
  const int row = blockIdx.x, t = threadIdx.x;
  const float4 rv = *(const float4*)(resid + (size_t)row * 1024 + t * 4);
  const s4v av = *(const s4v*)(attnb + (size_t)row * 1024 + t * 4);
  float x0 = rv.x + bf2f(av[0]), x1 = rv.y + bf2f(av[1]);
  float x2 = rv.z + bf2f(av[2]), x3 = rv.w + bf2f(av[3]);
  float s = x0 + x1 + x2 + x3;
  float ss = x0 * x0 + x1 * x1 + x2 * x2 + x3 * x3;
  for (int off = 32; off > 0; off >>= 1) {
    s += __shfl_down(s, off, 64);
    ss += __shfl_down(ss, off, 64);
  }
  __shared__ float red[8];
  const int wid = t >> 6, lane = t & 63;
  if (lane == 0) { red[wid] = s; red[4 + wid] = ss; }
  __syncthreads();
  float S = red[0] + red[1] + red[2] + red[3];
  float SS = red[4] + red[5] + red[6] + red[7];
  float mu = S * (1.f / 1024.f);
  float var = SS * (1.f / 1024.f) - mu * mu;
  float rstd = rsqrtf(var + 1e-5f);
  const float4 g = *(const float4*)(gamma + t * 4);
  const float4 bb = *(const float4*)(beta + t * 4);
  float4 o;
  o.x = (x0 - mu) * rstd * g.x + bb.x;
  o.y = (x1 - mu) * rstd * g.y + bb.y;
  o.z = (x2 - mu) * rstd * g.z + bb.z;
  o.w = (x3 - mu) * rstd * g.w + bb.w;
  *(float4*)(out + (size_t)row * 1024 + t * 4) = o;
}

extern "C" void kernel_launch(void* const* d_in, const int* in_sizes, int n_in,
                              void* d_out, int out_size, void* d_ws, size_t ws_size,
                              hipStream_t stream) {
  const float* Qin = (const float*)d_in[0];
  const float* Kin = (const float*)d_in[1];
  const float* Vin = (const float*)d_in[2];
  const float* Wq = (const float*)d_in[3];
  const float* bq = (const float*)d_in[4];
  const float* Wk = (const float*)d_in[5];
  const float* bk = (const float*)d_in[6];
  const float* Wv = (const float*)d_in[7];
  const float* bv = (const float*)d_in[8];
  const float* Wo = (const float*)d_in[9];
  const float* bo = (const float*)d_in[10];
  const float* gamma = (const float*)d_in[11];
  const float* beta = (const float*)d_in[12];
  float* out = (float*)d_out;

  char* ws = (char*)d_ws;
  const size_t MB = 1024 * 1024;
  short* Qp    = (short*)(ws);            // Qp,Kp,Vpt contiguous at z*8388608
  short* Ctx   = (short*)(ws + 48 * MB);
  short* AOutB = (short*)(ws + 64 * MB);
  short* Wt    = (short*)(ws + 80 * MB);  // 4 x 2MB

  wtrans4<<<dim3(16, 16, 4), 256, 0, stream>>>(Wq, Wk, Wv, Wo, Wt);

  const float qscale = 0.125f * 1.44269504f;  // 1/sqrt(64) * log2(e)

  gemm_bt<1, 0><<<dim3(64, 8, 3), 256, 0, stream>>>(
      Qin, Kin, Vin, nullptr, Wt, bq, bk, bv, qscale, Qp);

  attn_kernel<<<dim3(8, 64), 256, 0, stream>>>(Qp, Qp + 8388608, Qp + 16777216, Ctx);

  gemm_bt<0, 1><<<dim3(64, 8, 1), 256, 0, stream>>>(
      nullptr, nullptr, nullptr, Ctx, Wt + 3 * 1048576, bo, bo, bo, 1.f, AOutB);

  ln_kernel<<<8192, 256, 0, stream>>>(Qin, AOutB, gamma, beta, out);
}